// Round 11
// baseline (223.392 us; speedup 1.0000x reference)
//
#include <hip/hip_runtime.h>
#include <hip/hip_bf16.h>

#define D_FEAT 64
#define OVF_CAP 65536
#define EB 4096              // edges per bin block
#define NBMAX 1024           // max buckets (128 nodes each -> n <= 131072)
#define CAPB 4096            // bucket segment capacity
#define CSL 32               // slots per node

typedef unsigned int uint32;

__device__ inline float blo(uint32 u) { return __uint_as_float(u << 16); }
__device__ inline float bhi(uint32 u) { return __uint_as_float(u & 0xffff0000u); }
__device__ inline float dinv(int d) { return (d > 0) ? rsqrtf((float)d) : 0.0f; }

// ---- A: bin edges into CAP-padded 128-node bucket segments + EXACT degree
//      via global atomics (400KB L2-resident table). r6's proven shape
//      (391 blocks x 1024 thr, <61us measured bound), cast removed.
__global__ __launch_bounds__(1024) void k_bin(const int* __restrict__ row,
                                              const int* __restrict__ col,
                                              int* __restrict__ deg,
                                              int* __restrict__ cursor,
                                              uint32* __restrict__ binned,
                                              int2* __restrict__ ovf,
                                              int* __restrict__ ovf_cnt,
                                              int E, int nb) {
    __shared__ int h[NBMAX];
    for (int i = threadIdx.x; i < nb; i += 1024) h[i] = 0;
    __syncthreads();
    const int s = blockIdx.x * EB;
    const int e = (s + EB < E) ? s + EB : E;
    for (int i = s + threadIdx.x; i < e; i += 1024) {
        int c = col[i];
        atomicAdd(&h[c >> 7], 1);
        atomicAdd(&deg[c], 1);               // exact degree (all edges)
    }
    __syncthreads();
    for (int k = threadIdx.x; k < nb; k += 1024) {
        int c = h[k];
        if (c) h[k] = atomicAdd(&cursor[k], c);   // one reservation per bucket
    }
    __syncthreads();
    for (int i = s + threadIdx.x; i < e; i += 1024) {
        int c = col[i];
        uint32 r = (uint32)row[i];
        int b = c >> 7;
        int pos = atomicAdd(&h[b], 1);
        if (pos < CAPB) {
            binned[(size_t)b * CAPB + pos] = (r << 7) | (uint32)(c & 127);
        } else {                             // segment full: exact fixup later
            int o = atomicAdd(ovf_cnt, 1);
            if (o < OVF_CAP) ovf[o] = make_int2((int)r, c);
        }
    }
}

// ---- W: winv table + PRE-SCALED bf16 cast: xb[j] = bf16(x_j * dinv(deg_j)).
//      Removes the per-source weight (winv[s] dependent load) from the gather
//      inner loop entirely -- sources' scale is baked into the bf16 row.
__global__ __launch_bounds__(256) void k_wcast(const int* __restrict__ deg,
                                               float* __restrict__ winv,
                                               const float2* __restrict__ x2,
                                               uint32* __restrict__ xb,
                                               int n, int nhalf) {
    const int t = blockIdx.x * 256 + threadIdx.x;
    const int stride = gridDim.x * 256;
    for (int i = t; i < n; i += stride) winv[i] = dinv(deg[i]);
    for (int j = t; j < nhalf; j += stride) {
        int node = j >> 5;                   // 32 float2 per node row
        float w = dinv(deg[node]);           // direct from deg: no winv race
        float2 v = x2[j];
        __hip_bfloat16 bx = __float2bfloat16(v.x * w);
        __hip_bfloat16 by = __float2bfloat16(v.y * w);
        uint32 ux = *reinterpret_cast<unsigned short*>(&bx);
        uint32 uy = *reinterpret_cast<unsigned short*>(&by);
        xb[j] = ux | (uy << 16);
    }
}

// ---- B: fused rank + gather. Block owns 128 nodes: rank its bucket segment
//      into LDS slots (slots never touch global: -25.6MB RW vs r6), then the
//      verified 4-edge-parallel gather over PRE-SCALED rows (no per-source
//      weight load). No grid barrier needed thanks to k_wcast.
__global__ __launch_bounds__(512) void k_rgather(const int* __restrict__ cursor,
                                                 const uint32* __restrict__ binned,
                                                 const float* __restrict__ winv,
                                                 const uint32* __restrict__ xb,
                                                 const float4* __restrict__ x4,
                                                 const float* __restrict__ alpha_p,
                                                 const float* __restrict__ rs_p,
                                                 float4* __restrict__ out4,
                                                 int2* __restrict__ ovf,
                                                 int* __restrict__ ovf_cnt,
                                                 int n) {
    __shared__ int   slots[128 * CSL];       // 16 KB
    __shared__ int   cnt[128];
    __shared__ float winvl[128];
    const int bid = blockIdx.x;
    const int tid = threadIdx.x;
    if (tid < 128) cnt[tid] = 0;
    __syncthreads();
    const int base = bid << 7;
    int tot = cursor[bid];
    if (tot > CAPB) tot = CAPB;
    const uint32* seg = binned + (size_t)bid * CAPB;
    for (int i = tid; i < tot; i += 512) {
        uint32 pk = seg[i];
        int cl = (int)(pk & 127);
        int r  = (int)(pk >> 7);
        int rk = atomicAdd(&cnt[cl], 1);     // LDS atomic
        if (rk < CSL) {
            slots[(cl << 5) + rk] = r;
        } else {                             // node over CSL: exact fixup
            int o = atomicAdd(ovf_cnt, 1);
            if (o < OVF_CAP) ovf[o] = make_int2(r, base + cl);
        }
    }
    __syncthreads();
    if (tid < 128) {
        int node = base + tid;
        winvl[tid] = (node < n) ? winv[node] : 0.f;
    }
    __syncthreads();

    const int wv   = tid >> 6;               // wave 0..7
    const int lane = tid & 63;
    const int q = lane >> 4;                 // edge group 0..3
    const int l = lane & 15;                 // float4 index in row
    const float alpha = *alpha_p;
    const float rs = *rs_p;
    for (int nl = (wv << 4); nl < (wv << 4) + 16; ++nl) {   // 16 nodes/wave
        int node = base + nl;
        if (node >= n) break;                // wave-uniform exit
        int e = cnt[nl];
        if (e > CSL) e = CSL;
        float4 xr = make_float4(0.f, 0.f, 0.f, 0.f);
        if (q == 0) xr = x4[(size_t)node * 16 + l];   // hoisted residual
        const int* sl = &slots[nl << 5];
        float ax = 0.f, ay = 0.f, az = 0.f, aw = 0.f;
        int k = 0;
        for (; k + 16 <= e; k += 16) {       // 4 edges in flight, no weights
            int s0 = sl[k + q];
            int s1 = sl[k + 4 + q];
            int s2 = sl[k + 8 + q];
            int s3 = sl[k + 12 + q];
            uint2 p0 = ((const uint2*)(xb + (size_t)s0 * 32))[l];
            uint2 p1 = ((const uint2*)(xb + (size_t)s1 * 32))[l];
            uint2 p2 = ((const uint2*)(xb + (size_t)s2 * 32))[l];
            uint2 p3 = ((const uint2*)(xb + (size_t)s3 * 32))[l];
            ax += blo(p0.x); ay += bhi(p0.x); az += blo(p0.y); aw += bhi(p0.y);
            ax += blo(p1.x); ay += bhi(p1.x); az += blo(p1.y); aw += bhi(p1.y);
            ax += blo(p2.x); ay += bhi(p2.x); az += blo(p2.y); aw += bhi(p2.y);
            ax += blo(p3.x); ay += bhi(p3.x); az += blo(p3.y); aw += bhi(p3.y);
        }
        for (; k < e; k += 4) {
            int kk = k + q;
            if (kk < e) {
                int s0 = sl[kk];
                uint2 p0 = ((const uint2*)(xb + (size_t)s0 * 32))[l];
                ax += blo(p0.x); ay += bhi(p0.x);
                az += blo(p0.y); aw += bhi(p0.y);
            }
        }
        ax += __shfl_down(ax, 32, 64); ay += __shfl_down(ay, 32, 64);
        az += __shfl_down(az, 32, 64); aw += __shfl_down(aw, 32, 64);
        ax += __shfl_down(ax, 16, 64); ay += __shfl_down(ay, 16, 64);
        az += __shfl_down(az, 16, 64); aw += __shfl_down(aw, 16, 64);
        if (q == 0) {
            float adw = alpha * winvl[nl];
            float4 o;
            o.x = fmaf(adw, ax, rs * xr.x);
            o.y = fmaf(adw, ay, rs * xr.y);
            o.z = fmaf(adw, az, rs * xr.z);
            o.w = fmaf(adw, aw, rs * xr.w);
            out4[(size_t)node * 16 + l] = o;
        }
    }
}

// ---- overflow fix-up (CAPB or CSL overflow; empty for uniform input) ----
__global__ void k_ovf(const int2* __restrict__ ovf, const int* __restrict__ cnt_p,
                      const float* __restrict__ x, const float* __restrict__ winv,
                      const float* __restrict__ alpha_p, float* __restrict__ out) {
    int cnt = *cnt_p;
    if (cnt > OVF_CAP) cnt = OVF_CAP;
    if (cnt <= 0) return;
    float a = *alpha_p;
    long long total = (long long)cnt * 64;
    long long stride = (long long)gridDim.x * blockDim.x;
    for (long long idx = blockIdx.x * (long long)blockDim.x + threadIdx.x;
         idx < total; idx += stride) {
        int e = (int)(idx >> 6);
        int f = (int)(idx & 63);
        int2 rc = ovf[e];
        float w = a * winv[rc.x] * winv[rc.y];
        atomicAdd(&out[(size_t)rc.y * D_FEAT + f], w * x[(size_t)rc.x * D_FEAT + f]);
    }
}

// ---- winv table for the fallback path ----
__global__ void k_winv(const int* __restrict__ deg, float* __restrict__ winv, int n) {
    int i = blockIdx.x * blockDim.x + threadIdx.x;
    if (i < n) winv[i] = dinv(deg[i]);
}

// ================= fallback: direct padded-CSR build (round 4) ===============
__global__ __launch_bounds__(256) void k_prep(const float2* __restrict__ x2,
                                              uint32* __restrict__ xb,
                                              const int* __restrict__ row,
                                              const int* __restrict__ col,
                                              int* __restrict__ deg,
                                              int* __restrict__ slots,
                                              int2* __restrict__ ovf,
                                              int* __restrict__ ovf_cnt,
                                              int nhalf, int E, int C) {
    const int t = blockIdx.x * blockDim.x + threadIdx.x;
    if (t < E) {
        int c = col[t];
        int r = row[t];
        int rk = atomicAdd(&deg[c], 1);
        if (rk < C) {
            slots[(size_t)c * C + rk] = r;
        } else {
            int o = atomicAdd(ovf_cnt, 1);
            if (o < OVF_CAP) ovf[o] = make_int2(r, c);
        }
    }
    const int stride = gridDim.x * blockDim.x;
    for (int j = t; j < nhalf; j += stride) {
        float2 v = x2[j];
        __hip_bfloat16 bx = __float2bfloat16(v.x);
        __hip_bfloat16 by = __float2bfloat16(v.y);
        uint32 ux = *reinterpret_cast<unsigned short*>(&bx);
        uint32 uy = *reinterpret_cast<unsigned short*>(&by);
        xb[j] = ux | (uy << 16);
    }
}

// fallback gather (global slots, UNscaled xb -> per-source winv applied)
__global__ void k_gather4d(const uint32* __restrict__ xb,
                           const float4* __restrict__ x4,
                           const int* __restrict__ deg,
                           const float* __restrict__ winv,
                           const int* __restrict__ slots,
                           const float* __restrict__ alpha_p,
                           const float* __restrict__ rs_p,
                           float4* __restrict__ out4, int n, int C) {
    int wid = (blockIdx.x * blockDim.x + threadIdx.x) >> 6;
    if (wid >= n) return;
    const int lane = threadIdx.x & 63;
    const int q = lane >> 4;
    const int l = lane & 15;
    int d = deg[wid];
    int e = (d < C) ? d : C;
    float4 xr = make_float4(0.f, 0.f, 0.f, 0.f);
    if (q == 0) xr = x4[(size_t)wid * 16 + l];
    const int* sl = slots + (size_t)wid * C;
    float ax = 0.f, ay = 0.f, az = 0.f, aw = 0.f;
    int k = 0;
    for (; k + 16 <= e; k += 16) {
        int s0 = sl[k + q];
        int s1 = sl[k + 4 + q];
        int s2 = sl[k + 8 + q];
        int s3 = sl[k + 12 + q];
        float w0 = winv[s0], w1 = winv[s1], w2 = winv[s2], w3 = winv[s3];
        uint2 p0 = ((const uint2*)(xb + (size_t)s0 * 32))[l];
        uint2 p1 = ((const uint2*)(xb + (size_t)s1 * 32))[l];
        uint2 p2 = ((const uint2*)(xb + (size_t)s2 * 32))[l];
        uint2 p3 = ((const uint2*)(xb + (size_t)s3 * 32))[l];
        ax = fmaf(w0, blo(p0.x), ax); ay = fmaf(w0, bhi(p0.x), ay);
        az = fmaf(w0, blo(p0.y), az); aw = fmaf(w0, bhi(p0.y), aw);
        ax = fmaf(w1, blo(p1.x), ax); ay = fmaf(w1, bhi(p1.x), ay);
        az = fmaf(w1, blo(p1.y), az); aw = fmaf(w1, bhi(p1.y), aw);
        ax = fmaf(w2, blo(p2.x), ax); ay = fmaf(w2, bhi(p2.x), ay);
        az = fmaf(w2, blo(p2.y), az); aw = fmaf(w2, bhi(p2.y), aw);
        ax = fmaf(w3, blo(p3.x), ax); ay = fmaf(w3, bhi(p3.x), ay);
        az = fmaf(w3, blo(p3.y), az); aw = fmaf(w3, bhi(p3.y), aw);
    }
    for (; k < e; k += 4) {
        int kk = k + q;
        if (kk < e) {
            int s0 = sl[kk];
            float w0 = winv[s0];
            uint2 p0 = ((const uint2*)(xb + (size_t)s0 * 32))[l];
            ax = fmaf(w0, blo(p0.x), ax); ay = fmaf(w0, bhi(p0.x), ay);
            az = fmaf(w0, blo(p0.y), az); aw = fmaf(w0, bhi(p0.y), aw);
        }
    }
    ax += __shfl_down(ax, 32, 64); ay += __shfl_down(ay, 32, 64);
    az += __shfl_down(az, 32, 64); aw += __shfl_down(aw, 32, 64);
    ax += __shfl_down(ax, 16, 64); ay += __shfl_down(ay, 16, 64);
    az += __shfl_down(az, 16, 64); aw += __shfl_down(aw, 16, 64);
    if (q == 0) {
        float adw = (*alpha_p) * winv[wid];
        float rs  = *rs_p;
        float4 o;
        o.x = fmaf(adw, ax, rs * xr.x);
        o.y = fmaf(adw, ay, rs * xr.y);
        o.z = fmaf(adw, az, rs * xr.z);
        o.w = fmaf(adw, aw, rs * xr.w);
        out4[(size_t)wid * 16 + l] = o;
    }
}

static inline char* align_up(char* p, size_t a) {
    return (char*)(((uintptr_t)p + (a - 1)) & ~(uintptr_t)(a - 1));
}

extern "C" void kernel_launch(void* const* d_in, const int* in_sizes, int n_in,
                              void* d_out, int out_size, void* d_ws, size_t ws_size,
                              hipStream_t stream) {
    const float* x         = (const float*)d_in[0];
    const float* alpha     = (const float*)d_in[1];
    const float* res_scale = (const float*)d_in[2];
    const int*   ei        = (const int*)d_in[3];

    const int n = in_sizes[0] / D_FEAT;      // 100000
    const int E = in_sizes[3] / 2;           // 1600000
    const int* row = ei;                     // sources
    const int* col = ei + E;                 // targets

    float* out = (float*)d_out;
    const int nhalf = n * (D_FEAT / 2);
    const int nb = (n + 127) >> 7;           // 128-node buckets (782)
    const int B1 = (E + EB - 1) / EB;        // bin blocks (391)

    // ---------- bin -> wcast(pre-scale) -> fused rank+gather ----------
    {
        char* p = (char*)d_ws;
        int*    deg     = (int*)p;            p += (size_t)n * 4;
        int*    cursor  = (int*)p;            p += (size_t)nb * 4;
        int*    ovf_cnt = (int*)p;            p += 4;
        float*  winv    = (float*)p;          p += (size_t)n * 4;
        int2*   ovf     = (int2*)p;           p += (size_t)OVF_CAP * 8;
        p = align_up(p, 16);
        uint32* xb      = (uint32*)p;         p += (size_t)n * 128;
        p = align_up(p, 16);
        uint32* binned  = (uint32*)p;         p += (size_t)nb * CAPB * 4;
        const size_t need = (size_t)(p - (char*)d_ws);

        const bool ok = (need <= ws_size) && (nb <= NBMAX) && (n <= (NBMAX << 7));
        if (ok) {
            // zero deg + cursor + ovf_cnt (contiguous)
            hipMemsetAsync(deg, 0, (size_t)(n + nb + 1) * 4, stream);
            k_bin<<<B1, 1024, 0, stream>>>(row, col, deg, cursor, binned,
                                           ovf, ovf_cnt, E, nb);
            int wblocks = (nhalf + 255) / 256;
            if (wblocks > 1024) wblocks = 1024;
            k_wcast<<<wblocks, 256, 0, stream>>>(deg, winv, (const float2*)x, xb,
                                                 n, nhalf);
            k_rgather<<<nb, 512, 0, stream>>>(cursor, binned, winv, xb,
                                              (const float4*)x, alpha, res_scale,
                                              (float4*)out, ovf, ovf_cnt, n);
            k_ovf<<<64, 256, 0, stream>>>(ovf, ovf_cnt, x, winv, alpha, out);
            return;
        }
    }

    // ---------- fallback: direct scatter build (round-4 path) ----------
    {
        char* q = (char*)d_ws;
        int*    degf    = (int*)q;            q += (size_t)n * 4;
        int*    ovf_cf  = (int*)q;            q += 4;
        float*  winvf   = (float*)q;          q += (size_t)n * 4;
        int2*   ovff    = (int2*)q;           q += (size_t)OVF_CAP * 8;
        q = align_up(q, 16);
        uint32* xbf     = (uint32*)q;         q += (size_t)n * 128;
        int*    slotsf  = (int*)q;
        const size_t fxd = (size_t)(q - (char*)d_ws);
        int Cf = 0;
        if (ws_size > fxd) {
            size_t c_avail = (ws_size - fxd) / ((size_t)n * 4);
            Cf = (c_avail > 32) ? 32 : (int)c_avail;
        }
        if (Cf < 1) return;
        hipMemsetAsync(degf, 0, (size_t)n * 4 + 4, stream);
        k_prep<<<(E + 255) / 256, 256, 0, stream>>>(
            (const float2*)x, xbf, row, col, degf, slotsf, ovff, ovf_cf,
            nhalf, E, Cf);
        k_winv<<<(n + 255) / 256, 256, 0, stream>>>(degf, winvf, n);
        const long long tt = (long long)n * D_FEAT;
        const int blocks = (int)((tt + 255) / 256);
        k_gather4d<<<blocks, 256, 0, stream>>>(xbf, (const float4*)x, degf, winvf,
                                               slotsf, alpha, res_scale,
                                               (float4*)out, n, Cf);
        k_ovf<<<64, 256, 0, stream>>>(ovff, ovf_cf, x, winvf, alpha, out);
    }
}

// Round 12
// 190.886 us; speedup vs baseline: 1.1703x; 1.1703x over previous
//
#include <hip/hip_runtime.h>
#include <hip/hip_bf16.h>

#define D_FEAT 64
#define OVF_CAP 65536
#define EB 4096              // edges per split block
#define NBMAX 1024           // max buckets (128 nodes each -> n <= 131072)
#define CSL 32               // slots per node

typedef unsigned int uint32;

__device__ inline float blo(uint32 u) { return __uint_as_float(u << 16); }
__device__ inline float bhi(uint32 u) { return __uint_as_float(u & 0xffff0000u); }
__device__ inline float dinv(int d) { return (d > 0) ? rsqrtf((float)d) : 0.0f; }

// ---- pass 1: LDS-staged bucket sort. Per block: hist -> LDS prefix scan ->
//      scatter edges INTO LDS -> write the block's region fully packed
//      (coalesced, written once) + block-major offset table.
//      Zero scattered global writes, zero global atomics (r11's k_bin showed
//      scattered 4B binned writes cost 64MB writeback = ~75us; r6's scatter
//      paid the same).
__global__ __launch_bounds__(1024) void k_split(const int* __restrict__ row,
                                                const int* __restrict__ col,
                                                const float2* __restrict__ x2,
                                                uint32* __restrict__ xb,
                                                uint32* __restrict__ binned2,
                                                int* __restrict__ off,
                                                int nhalf, int E, int nb, int B) {
    __shared__ int    h[NBMAX];        // hist -> cursor
    __shared__ int    P[1024];         // scan workspace
    __shared__ uint32 st[EB];          // staged edges (16 KB)
    const int tid = threadIdx.x;
    const int b = blockIdx.x;
    for (int i = tid; i < nb; i += 1024) h[i] = 0;
    __syncthreads();
    const int s = b * EB;
    const int e = (s + EB < E) ? s + EB : E;
    // histogram (LDS atomics only)
    for (int i = s + tid; i < e; i += 1024)
        atomicAdd(&h[col[i] >> 7], 1);
    __syncthreads();
    // inclusive Hillis-Steele scan over nb buckets (nb <= 1024)
    P[tid] = (tid < nb) ? h[tid] : 0;
    __syncthreads();
    for (int o = 1; o < 1024; o <<= 1) {
        int v = P[tid];
        if (tid >= o) v += P[tid - o];
        __syncthreads();
        P[tid] = v;
        __syncthreads();
    }
    int cntk = 0, excl = 0;
    if (tid < nb) { cntk = h[tid]; excl = P[tid] - cntk; }
    __syncthreads();
    if (tid < nb) {
        h[tid] = excl;                                 // LDS cursor
        off[(size_t)b * (nb + 1) + tid] = excl;        // packed (block-major)
    }
    if (tid == 0) off[(size_t)b * (nb + 1) + nb] = e - s;   // sentinel
    __syncthreads();
    // scatter into LDS (bucket-sorted within the block)
    for (int i = s + tid; i < e; i += 1024) {
        int c = col[i];
        uint32 r = (uint32)row[i];
        int pos = atomicAdd(&h[c >> 7], 1);            // LDS atomic
        st[pos] = (r << 7) | (uint32)(c & 127);
    }
    __syncthreads();
    // packed region write: consecutive lanes -> consecutive addresses
    const int tot = e - s;
    uint32* dst = binned2 + (size_t)b * EB;
    for (int i = tid; i < tot; i += 1024) dst[i] = st[i];
    // fused bf16 cast, node-major linear
    const int t = b * 1024 + tid;
    const int stride = B * 1024;
    for (int j = t; j < nhalf; j += stride) {
        float2 v = x2[j];
        __hip_bfloat16 bx = __float2bfloat16(v.x);
        __hip_bfloat16 by = __float2bfloat16(v.y);
        uint32 ux = *reinterpret_cast<unsigned short*>(&bx);
        uint32 uy = *reinterpret_cast<unsigned short*>(&by);
        xb[j] = ux | (uy << 16);
    }
}

// ---- pass 2: bucket k pulls its slice from each block region (off table is
//      1.2MB -> L2-resident; slices ~5 entries), ranks via LDS atomics, writes
//      slots into its block-PRIVATE window (single-writer, r6-proven), emits
//      deg + winv. No overflow paths except deg > CSL.
__global__ __launch_bounds__(512) void k_build(const uint32* __restrict__ binned2,
                                               const int* __restrict__ off,
                                               int* __restrict__ slots,
                                               int* __restrict__ deg,
                                               float* __restrict__ winv,
                                               int2* __restrict__ ovf,
                                               int* __restrict__ ovf_cnt,
                                               int n, int nb, int B) {
    __shared__ int cnt[128];
    const int k = blockIdx.x;
    const int tid = threadIdx.x;
    if (tid < 128) cnt[tid] = 0;
    __syncthreads();
    const int base = k << 7;
    for (int b = tid; b < B; b += 512) {
        const int* ob = off + (size_t)b * (nb + 1) + k;
        int o0 = ob[0], o1 = ob[1];                   // adjacent: one 8B read
        const uint32* sl = binned2 + (size_t)b * EB;
        for (int i = o0; i < o1; ++i) {
            uint32 pk = sl[i];
            int cl = (int)(pk & 127);
            int r  = (int)(pk >> 7);
            int rk = atomicAdd(&cnt[cl], 1);          // LDS atomic
            if (rk < CSL) {
                slots[(size_t)(base + cl) * CSL + rk] = r;
            } else {
                int o = atomicAdd(ovf_cnt, 1);
                if (o < OVF_CAP) ovf[o] = make_int2(r, base + cl);
            }
        }
    }
    __syncthreads();
    if (tid < 128) {
        int node = base + tid;
        if (node < n) {
            int d = cnt[tid];
            deg[node] = d;
            winv[node] = dinv(d);
        }
    }
}

// ---- gather: one wave per node, 4 edges in parallel, 16-edge unroll ----
// (verified body: ~61 us, random-128B-fetch limited — do not touch)
__global__ void k_gather4d(const uint32* __restrict__ xb,
                           const float4* __restrict__ x4,
                           const int* __restrict__ deg,
                           const float* __restrict__ winv,
                           const int* __restrict__ slots,
                           const float* __restrict__ alpha_p,
                           const float* __restrict__ rs_p,
                           float4* __restrict__ out4, int n, int C) {
    int wid = (blockIdx.x * blockDim.x + threadIdx.x) >> 6;
    if (wid >= n) return;
    const int lane = threadIdx.x & 63;
    const int q = lane >> 4;
    const int l = lane & 15;
    int d = deg[wid];
    int e = (d < C) ? d : C;
    float4 xr = make_float4(0.f, 0.f, 0.f, 0.f);
    if (q == 0) xr = x4[(size_t)wid * 16 + l];   // hoisted residual load
    const int* sl = slots + (size_t)wid * C;
    float ax = 0.f, ay = 0.f, az = 0.f, aw = 0.f;
    int k = 0;
    for (; k + 16 <= e; k += 16) {
        int s0 = sl[k + q];
        int s1 = sl[k + 4 + q];
        int s2 = sl[k + 8 + q];
        int s3 = sl[k + 12 + q];
        float w0 = winv[s0], w1 = winv[s1], w2 = winv[s2], w3 = winv[s3];
        uint2 p0 = ((const uint2*)(xb + (size_t)s0 * 32))[l];
        uint2 p1 = ((const uint2*)(xb + (size_t)s1 * 32))[l];
        uint2 p2 = ((const uint2*)(xb + (size_t)s2 * 32))[l];
        uint2 p3 = ((const uint2*)(xb + (size_t)s3 * 32))[l];
        ax = fmaf(w0, blo(p0.x), ax); ay = fmaf(w0, bhi(p0.x), ay);
        az = fmaf(w0, blo(p0.y), az); aw = fmaf(w0, bhi(p0.y), aw);
        ax = fmaf(w1, blo(p1.x), ax); ay = fmaf(w1, bhi(p1.x), ay);
        az = fmaf(w1, blo(p1.y), az); aw = fmaf(w1, bhi(p1.y), aw);
        ax = fmaf(w2, blo(p2.x), ax); ay = fmaf(w2, bhi(p2.x), ay);
        az = fmaf(w2, blo(p2.y), az); aw = fmaf(w2, bhi(p2.y), aw);
        ax = fmaf(w3, blo(p3.x), ax); ay = fmaf(w3, bhi(p3.x), ay);
        az = fmaf(w3, blo(p3.y), az); aw = fmaf(w3, bhi(p3.y), aw);
    }
    for (; k < e; k += 4) {
        int kk = k + q;
        if (kk < e) {
            int s0 = sl[kk];
            float w0 = winv[s0];
            uint2 p0 = ((const uint2*)(xb + (size_t)s0 * 32))[l];
            ax = fmaf(w0, blo(p0.x), ax); ay = fmaf(w0, bhi(p0.x), ay);
            az = fmaf(w0, blo(p0.y), az); aw = fmaf(w0, bhi(p0.y), aw);
        }
    }
    ax += __shfl_down(ax, 32, 64); ay += __shfl_down(ay, 32, 64);
    az += __shfl_down(az, 32, 64); aw += __shfl_down(aw, 32, 64);
    ax += __shfl_down(ax, 16, 64); ay += __shfl_down(ay, 16, 64);
    az += __shfl_down(az, 16, 64); aw += __shfl_down(aw, 16, 64);
    if (q == 0) {
        float adw = (*alpha_p) * winv[wid];
        float rs  = *rs_p;
        float4 o;
        o.x = fmaf(adw, ax, rs * xr.x);
        o.y = fmaf(adw, ay, rs * xr.y);
        o.z = fmaf(adw, az, rs * xr.z);
        o.w = fmaf(adw, aw, rs * xr.w);
        out4[(size_t)wid * 16 + l] = o;
    }
}

// ---- overflow fix-up (deg>CSL only; empty for uniform input) ----
__global__ void k_ovf(const int2* __restrict__ ovf, const int* __restrict__ cnt_p,
                      const float* __restrict__ x, const float* __restrict__ winv,
                      const float* __restrict__ alpha_p, float* __restrict__ out) {
    int cnt = *cnt_p;
    if (cnt > OVF_CAP) cnt = OVF_CAP;
    if (cnt <= 0) return;
    float a = *alpha_p;
    long long total = (long long)cnt * 64;
    long long stride = (long long)gridDim.x * blockDim.x;
    for (long long idx = blockIdx.x * (long long)blockDim.x + threadIdx.x;
         idx < total; idx += stride) {
        int e = (int)(idx >> 6);
        int f = (int)(idx & 63);
        int2 rc = ovf[e];
        float w = a * winv[rc.x] * winv[rc.y];
        atomicAdd(&out[(size_t)rc.y * D_FEAT + f], w * x[(size_t)rc.x * D_FEAT + f]);
    }
}

// ---- winv table for the fallback path ----
__global__ void k_winv(const int* __restrict__ deg, float* __restrict__ winv, int n) {
    int i = blockIdx.x * blockDim.x + threadIdx.x;
    if (i < n) winv[i] = dinv(deg[i]);
}

// ================= fallback: direct padded-CSR build (round 4) ===============
__global__ __launch_bounds__(256) void k_prep(const float2* __restrict__ x2,
                                              uint32* __restrict__ xb,
                                              const int* __restrict__ row,
                                              const int* __restrict__ col,
                                              int* __restrict__ deg,
                                              int* __restrict__ slots,
                                              int2* __restrict__ ovf,
                                              int* __restrict__ ovf_cnt,
                                              int nhalf, int E, int C) {
    const int t = blockIdx.x * blockDim.x + threadIdx.x;
    if (t < E) {
        int c = col[t];
        int r = row[t];
        int rk = atomicAdd(&deg[c], 1);
        if (rk < C) {
            slots[(size_t)c * C + rk] = r;
        } else {
            int o = atomicAdd(ovf_cnt, 1);
            if (o < OVF_CAP) ovf[o] = make_int2(r, c);
        }
    }
    const int stride = gridDim.x * blockDim.x;
    for (int j = t; j < nhalf; j += stride) {
        float2 v = x2[j];
        __hip_bfloat16 bx = __float2bfloat16(v.x);
        __hip_bfloat16 by = __float2bfloat16(v.y);
        uint32 ux = *reinterpret_cast<unsigned short*>(&bx);
        uint32 uy = *reinterpret_cast<unsigned short*>(&by);
        xb[j] = ux | (uy << 16);
    }
}

static inline char* align_up(char* p, size_t a) {
    return (char*)(((uintptr_t)p + (a - 1)) & ~(uintptr_t)(a - 1));
}

extern "C" void kernel_launch(void* const* d_in, const int* in_sizes, int n_in,
                              void* d_out, int out_size, void* d_ws, size_t ws_size,
                              hipStream_t stream) {
    const float* x         = (const float*)d_in[0];
    const float* alpha     = (const float*)d_in[1];
    const float* res_scale = (const float*)d_in[2];
    const int*   ei        = (const int*)d_in[3];

    const int n = in_sizes[0] / D_FEAT;      // 100000
    const int E = in_sizes[3] / 2;           // 1600000
    const int* row = ei;                     // sources
    const int* col = ei + E;                 // targets

    float* out = (float*)d_out;
    const int nhalf = n * (D_FEAT / 2);
    const int nb = (n + 127) >> 7;           // 128-node buckets (782)
    const int B  = (E + EB - 1) / EB;        // split blocks (391)

    // ---------- LDS-staged split (packed writes) -> build -> gather ----------
    {
        char* p = (char*)d_ws;
        int*    deg     = (int*)p;            p += (size_t)n * 4;
        int*    ovf_cnt = (int*)p;            p += 4;
        float*  winv    = (float*)p;          p += (size_t)n * 4;
        int2*   ovf     = (int2*)p;           p += (size_t)OVF_CAP * 8;
        p = align_up(p, 16);
        uint32* xb      = (uint32*)p;         p += (size_t)n * 128;
        int*    slots   = (int*)p;            p += (size_t)n * CSL * 4;
        p = align_up(p, 16);
        uint32* binned2 = (uint32*)p;         p += (size_t)B * EB * 4;
        int*    off     = (int*)p;            p += (size_t)B * (nb + 1) * 4;
        const size_t need = (size_t)(p - (char*)d_ws);

        const bool ok = (need <= ws_size) && (nb <= NBMAX) && (n <= (NBMAX << 7));
        if (ok) {
            hipMemsetAsync(ovf_cnt, 0, 4, stream);
            k_split<<<B, 1024, 0, stream>>>(row, col, (const float2*)x, xb,
                                            binned2, off, nhalf, E, nb, B);
            k_build<<<nb, 512, 0, stream>>>(binned2, off, slots, deg, winv,
                                            ovf, ovf_cnt, n, nb, B);
            const long long tt = (long long)n * D_FEAT;
            const int blocks = (int)((tt + 255) / 256);
            k_gather4d<<<blocks, 256, 0, stream>>>(xb, (const float4*)x, deg, winv,
                                                   slots, alpha, res_scale,
                                                   (float4*)out, n, CSL);
            k_ovf<<<64, 256, 0, stream>>>(ovf, ovf_cnt, x, winv, alpha, out);
            return;
        }
    }

    // ---------- fallback: direct scatter build (round-4 path) ----------
    {
        char* q = (char*)d_ws;
        int*    degf    = (int*)q;            q += (size_t)n * 4;
        int*    ovf_cf  = (int*)q;            q += 4;
        float*  winvf   = (float*)q;          q += (size_t)n * 4;
        int2*   ovff    = (int2*)q;           q += (size_t)OVF_CAP * 8;
        q = align_up(q, 16);
        uint32* xbf     = (uint32*)q;         q += (size_t)n * 128;
        int*    slotsf  = (int*)q;
        const size_t fxd = (size_t)(q - (char*)d_ws);
        int Cf = 0;
        if (ws_size > fxd) {
            size_t c_avail = (ws_size - fxd) / ((size_t)n * 4);
            Cf = (c_avail > 32) ? 32 : (int)c_avail;
        }
        if (Cf < 1) return;
        hipMemsetAsync(degf, 0, (size_t)n * 4 + 4, stream);
        k_prep<<<(E + 255) / 256, 256, 0, stream>>>(
            (const float2*)x, xbf, row, col, degf, slotsf, ovff, ovf_cf,
            nhalf, E, Cf);
        k_winv<<<(n + 255) / 256, 256, 0, stream>>>(degf, winvf, n);
        const long long tt = (long long)n * D_FEAT;
        const int blocks = (int)((tt + 255) / 256);
        k_gather4d<<<blocks, 256, 0, stream>>>(xbf, (const float4*)x, degf, winvf,
                                               slotsf, alpha, res_scale,
                                               (float4*)out, n, Cf);
        k_ovf<<<64, 256, 0, stream>>>(ovff, ovf_cf, x, winvf, alpha, out);
    }
}